// Round 17
// baseline (164.415 us; speedup 1.0000x reference)
//
#include <hip/hip_runtime.h>
#include <hip/hip_fp16.h>

#define B_ 2
#define L_ 2048
#define D_ 1024
#define H_ 16

typedef __attribute__((ext_vector_type(8))) _Float16 f16x8;
typedef __attribute__((ext_vector_type(4))) _Float16 f16x4;
typedef __attribute__((ext_vector_type(2))) __fp16 fp16x2;
typedef __attribute__((ext_vector_type(4))) float f32x4;

#define LOG2E 1.44269504088896f

__device__ __forceinline__ void gload_lds16(const void* g, void* l) {
  __builtin_amdgcn_global_load_lds(
      (const __attribute__((address_space(1))) unsigned int*)g,
      (__attribute__((address_space(3))) unsigned int*)l, 16, 0, 0);
}

// ---------------- merged prep (grid-stride, 4352 blocks) ----------------
__global__ __launch_bounds__(256) void prep(
    const float* __restrict__ x, const float* __restrict__ Wq,
    const float* __restrict__ Wk, const float* __restrict__ Wv,
    const float* __restrict__ Wo, const int* __restrict__ m,
    const float* __restrict__ rel_emb,
    __half* __restrict__ xh, __half* __restrict__ wqh, __half* __restrict__ wkh,
    __half* __restrict__ wvh, __half* __restrict__ woh,
    unsigned long long* __restrict__ bits, float* __restrict__ tab) {
  const int bid = blockIdx.x;
  if (bid < 2048) {
#pragma unroll
    for (int kk = 0; kk < 4; ++kk) {
      int i = bid * 1024 + kk * 256 + threadIdx.x;  // 2M float4 groups
      const float* src;
      __half* dst;
      int j;
      if (i < 1048576) {
        src = x; dst = xh; j = i;
      } else {
        int k = i - 1048576;
        int wsel = k >> 18;
        j = k & 262143;
        src = wsel == 0 ? Wq : (wsel == 1 ? Wk : (wsel == 2 ? Wv : Wo));
        dst = wsel == 0 ? wqh : (wsel == 1 ? wkh : (wsel == 2 ? wvh : woh));
      }
      float4 v = ((const float4*)src)[j];
      __half2* o = (__half2*)(dst + (size_t)j * 4);
      o[0] = __floats2half2_rn(v.x, v.y);
      o[1] = __floats2half2_rn(v.z, v.w);
    }
  } else if (bid < 4096) {
    int gw = (bid - 2048) * 4 + (threadIdx.x >> 6);  // wave id [0,8192)
    int lane = threadIdx.x & 63;
#pragma unroll
    for (int j = 0; j < 16; ++j) {
      int wword = gw * 16 + j;  // 131072 words total
      int v = m[(size_t)wword * 64 + lane];
      unsigned long long bal = __ballot(v != 0);
      if (lane == 0) bits[wword] = bal;
    }
  } else {
    int i = (bid - 4096) * 256 + threadIdx.x;
    if (i >= H_ * 4095) return;
    int h = i / 4095, idx = i - h * 4095;
    int rel = idx - 2047;
    int n = rel < 0 ? -rel : rel;
    int bkt;
    if (n < 8) {
      bkt = n;
    } else {
      float t = logf((float)n / 8.0f) / 2.772588722239781f * 8.0f;
      int v = 8 + (int)t;
      bkt = v < 15 ? v : 15;
    }
    if (rel > 0) bkt += 16;
    tab[i] = rel_emb[bkt * H_ + h] * LOG2E;
  }
}

// ---------------- GEMM core 128x128 (m97-regime: grid-TLP hides drains) ----
template <bool CT>
__device__ __forceinline__ void gemm_tile(const __half* __restrict__ A,
                                          const __half* __restrict__ Bw,
                                          int m0, int n0,
                                          __half* sA, __half* sB,
                                          f32x4 (&acc)[4][4],
                                          int lane, int wm, int wn, int t) {
  for (int k0 = 0; k0 < 1024; k0 += 64) {
    __syncthreads();
#pragma unroll
    for (int it = 0; it < 4; ++it) {
      int c = t + it * 256;
      int row = c >> 3, seg = c & 7;
      gload_lds16(A + ((size_t)(m0 + row) << 10) + k0 + seg * 8, sA + c * 8);
      gload_lds16(Bw + ((size_t)(n0 + row) << 10) + k0 + seg * 8, sB + c * 8);
    }
    __syncthreads();
#pragma unroll
    for (int kk = 0; kk < 2; ++kk) {
      const int off = kk * 32 + (lane >> 4) * 8;
      const int rr = lane & 15;
      f16x8 af[4], bf[4];
#pragma unroll
      for (int i = 0; i < 4; ++i) af[i] = *(const f16x8*)&sA[(wm * 64 + i * 16 + rr) * 64 + off];
#pragma unroll
      for (int i = 0; i < 4; ++i) bf[i] = *(const f16x8*)&sB[(wn * 64 + i * 16 + rr) * 64 + off];
#pragma unroll
      for (int mi = 0; mi < 4; ++mi)
#pragma unroll
        for (int ni = 0; ni < 4; ++ni) {
          if (CT)
            acc[mi][ni] = __builtin_amdgcn_mfma_f32_16x16x32_f16(bf[ni], af[mi], acc[mi][ni], 0, 0, 0);
          else
            acc[mi][ni] = __builtin_amdgcn_mfma_f32_16x16x32_f16(af[mi], bf[ni], acc[mi][ni], 0, 0, 0);
        }
    }
  }
}

// fused QKV projection: grid 768 linear, XCD-chunked (4 m-panels per XCD)
// V output layout: Vt[bh][kseg=k/8][d][8 halves]
__global__ __launch_bounds__(256) void gemm_qkv(
    const __half* __restrict__ xh,
    const __half* __restrict__ Wq, const __half* __restrict__ Wk, const __half* __restrict__ Wv,
    const float* __restrict__ bq, const float* __restrict__ bk, const float* __restrict__ bvv,
    __half* __restrict__ Qh, __half* __restrict__ Kh, __half* __restrict__ Vt) {
  __shared__ __align__(16) __half sA[128 * 64];
  __shared__ __align__(16) __half sB[128 * 64];
  const int lin = blockIdx.x;
  const int xcd = lin & 7, idx = lin >> 3;        // 96 per XCD
  const int m0 = (xcd * 4 + (idx & 3)) * 128;     // 4 x-panels resident per XCD
  const int ng = (idx >> 2) * 128;                // weight panel shared by 4 consecutive blocks
  const int widx = ng >> 10;
  const int n0 = ng & 1023;
  const __half* Bw = widx == 0 ? Wq : (widx == 1 ? Wk : Wv);
  const float* bias = widx == 0 ? bq : (widx == 1 ? bk : bvv);
  const int t = threadIdx.x, lane = t & 63, w = t >> 6;
  const int wm = w >> 1, wn = w & 1;
  const int lg = lane >> 4, lr = lane & 15;
  f32x4 acc[4][4] = {};
  if (widx == 2) {
    gemm_tile<false>(xh, Bw, m0, n0, sA, sB, acc, lane, wm, wn, t);
    // V epilogue: Vt[bh][l>>3][dd][l&7 .. +3], one 8B store (l&7 in {0,4})
#pragma unroll
    for (int mi = 0; mi < 4; ++mi)
#pragma unroll
      for (int ni = 0; ni < 4; ++ni) {
        int m = m0 + wm * 64 + mi * 16 + lg * 4;
        int n = n0 + wn * 64 + ni * 16 + lr;
        float bvx = bias[n];
        int b = m >> 11, l = m & 2047, hh = n >> 6, dd = n & 63;
        f32x4 a = acc[mi][ni];
        size_t base = ((size_t)((b * 16 + hh) * 256 + (l >> 3))) * 512 + dd * 8 + (l & 7);
        f16x4 pv;
#pragma unroll
        for (int r = 0; r < 4; ++r) pv[r] = (_Float16)(a[r] + bvx);
        *(f16x4*)(Vt + base) = pv;
      }
  } else {
    gemm_tile<true>(xh, Bw, m0, n0, sA, sB, acc, lane, wm, wn, t);
    __half* dst = widx == 0 ? Qh : Kh;
    // fold 1/sqrt(dk) AND log2e into Q (softmax done in log2 domain)
    const float scf = widx == 0 ? 0.125f * LOG2E : 1.0f;
#pragma unroll
    for (int mi = 0; mi < 4; ++mi)
#pragma unroll
      for (int ni = 0; ni < 4; ++ni) {
        int m = m0 + wm * 64 + mi * 16 + lr;        // l index
        int n = n0 + wn * 64 + ni * 16 + 4 * lg;    // d index (4 consecutive)
        f32x4 bb = *(const f32x4*)&bias[n];
        int b = m >> 11, l = m & 2047, hh = n >> 6, dd = n & 63;
        f16x4 ov;
#pragma unroll
        for (int r = 0; r < 4; ++r) ov[r] = (_Float16)((acc[mi][ni][r] + bb[r]) * scf);
        *(f16x4*)(dst + (((size_t)(b * 16 + hh)) * 2048 + l) * 64 + dd) = ov;
      }
  }
}

// output projection: 64x64 tiles, grid 1024 = 4 blocks/CU (R12-exact: best total)
__global__ __launch_bounds__(256) void gemm_out(
    const __half* __restrict__ AO, const __half* __restrict__ Wo,
    const float* __restrict__ bo, float* __restrict__ out) {
  __shared__ __align__(16) __half sA[64 * 64];
  __shared__ __align__(16) __half sB[64 * 64];
  const int lin = blockIdx.x;
  const int xcd = lin & 7, idx = lin >> 3;       // 128 per XCD
  const int m0 = (xcd * 8 + (idx & 7)) * 64;     // 8 m-panels resident per XCD
  const int n0 = (idx >> 3) * 64;
  const int t = threadIdx.x, lane = t & 63, w = t >> 6;
  const int wm = w >> 1, wn = w & 1;             // 2x2 waves of 32x32
  const int lg = lane >> 4, lr = lane & 15;
  f32x4 acc[2][2] = {};
  for (int k0 = 0; k0 < 1024; k0 += 64) {
    __syncthreads();
#pragma unroll
    for (int it = 0; it < 2; ++it) {
      int c = t + it * 256;
      int row = c >> 3, seg = c & 7;
      gload_lds16(AO + ((size_t)(m0 + row) << 10) + k0 + seg * 8, sA + c * 8);
      gload_lds16(Wo + ((size_t)(n0 + row) << 10) + k0 + seg * 8, sB + c * 8);
    }
    __syncthreads();
#pragma unroll
    for (int kk = 0; kk < 2; ++kk) {
      const int off = kk * 32 + lg * 8;
      f16x8 af[2], bf[2];
#pragma unroll
      for (int i = 0; i < 2; ++i) af[i] = *(const f16x8*)&sA[(wm * 32 + i * 16 + lr) * 64 + off];
#pragma unroll
      for (int i = 0; i < 2; ++i) bf[i] = *(const f16x8*)&sB[(wn * 32 + i * 16 + lr) * 64 + off];
#pragma unroll
      for (int mi = 0; mi < 2; ++mi)
#pragma unroll
        for (int ni = 0; ni < 2; ++ni)
          acc[mi][ni] = __builtin_amdgcn_mfma_f32_16x16x32_f16(bf[ni], af[mi], acc[mi][ni], 0, 0, 0);
    }
  }
  // C^T epilogue: float4 stores
#pragma unroll
  for (int mi = 0; mi < 2; ++mi)
#pragma unroll
    for (int ni = 0; ni < 2; ++ni) {
      int mm = m0 + wm * 32 + mi * 16 + lr;
      int nn = n0 + wn * 32 + ni * 16 + 4 * lg;
      f32x4 bb = *(const f32x4*)&bo[nn];
      f32x4 vv;
#pragma unroll
      for (int r = 0; r < 4; ++r) vv[r] = acc[mi][ni][r] + bb[r];
      *(f32x4*)(out + (size_t)mm * 1024 + nn) = vv;
    }
}

// ---------------- flash attention ----------------
// R16 structure + VALU diet: (1) middle-band bias rides the MFMA C-operand
// (loads pre-init s[ct]; the 16 v_add_f32 vanish); (2) ts2 multiply skipped in
// the middle band (it was x1.0); (3) mask word pre-shifted by 4lg once so per-ct
// extraction is an immediate bfe.
__device__ __forceinline__ void stage_kv(const __half* __restrict__ Kb,
                                         const __half* __restrict__ Vb, int kt,
                                         __half* kdst, __half* vdst, int t) {
#pragma unroll
  for (int it = 0; it < 2; ++it) {
    int c = t + it * 256;
    int row = c >> 3, seg = c & 7;
    int gs = (seg ^ row) & 7;
    gload_lds16(Kb + ((size_t)(kt + row) << 6) + gs * 8, kdst + c * 8);
    // V: slot (kq=c>>6, d=c&63) <- Vb[(kt/8 + kq)*512 + d*8], 16B coalesced
    gload_lds16(Vb + ((size_t)((kt >> 3) + (c >> 6)) << 9) + (c & 63) * 8, vdst + c * 8);
  }
}

__device__ __forceinline__ void attn_tile(
    const __half* kb, const __half* vb,
    unsigned long long mwv, int diff,
    f16x8 aq0, f16x8 aq1,
    const float* sbias, const __half2* lutm2,
    float c_neg, float c_pos, int lg, int lr,
    f32x4 (&o)[4], f32x4& osum, f16x4 ones) {
  const bool mid = (diff < 143) && (diff > -191);  // wave-uniform
  // bias C-init (middle band): s starts as bias, QK^T accumulates on top
  f32x4 s[4];
  if (mid) {
    const int ibase = diff + 4 * lg - lr + 128;
#pragma unroll
    for (int ct = 0; ct < 4; ++ct)
#pragma unroll
      for (int r = 0; r < 4; ++r) {
        int idx = ibase + 16 * ct + r;
        idx = idx < 0 ? 0 : (idx > 256 ? 256 : idx);
        s[ct][r] = sbias[idx];
      }
  } else {
#pragma unroll
    for (int ct = 0; ct < 4; ++ct) s[ct] = f32x4{0.f, 0.f, 0.f, 0.f};
  }

  // S^T = bias + K Q^T (lane: q=lr, k=16ct+4lg+r); scale+log2e folded in Q
  __builtin_amdgcn_s_setprio(1);
#pragma unroll
  for (int ct = 0; ct < 4; ++ct) {
    int row = ct * 16 + lr;
    const __half* rb = &kb[row * 64];
    f16x8 kf0 = *(const f16x8*)(rb + ((8 * lg) ^ ((row & 7) << 3)));
    f16x8 kf1 = *(const f16x8*)(rb + ((32 + 8 * lg) ^ ((row & 7) << 3)));
    s[ct] = __builtin_amdgcn_mfma_f32_16x16x32_f16(kf0, aq0, s[ct], 0, 0, 0);
    s[ct] = __builtin_amdgcn_mfma_f32_16x16x32_f16(kf1, aq1, s[ct], 0, 0, 0);
  }
  __builtin_amdgcn_s_setprio(0);

  // V lane base: all 16 V reads = vbase + (ct*1024 + dt*128) halves (immediates)
  const __half* vbase = vb + ((lg >> 1) * 512 + lr * 8 + (lg & 1) * 4);

  // issue first V fragment group now: latency hides under softmax VALU
  f16x4 bvA[4], bvB[4];
#pragma unroll
  for (int dt = 0; dt < 4; ++dt)
    bvA[dt] = *(const f16x4*)(vbase + dt * 128);

  // mask word pre-shifted once; per-ct extraction = immediate bfe
  const unsigned long long mws = mwv >> (4 * lg);

  // P = [tsc *] exp2(S), mask via f16 LUT multiply
  f16x4 pa[4];
  if (mid) {
#pragma unroll
    for (int ct = 0; ct < 4; ++ct) {
      unsigned bits = (unsigned)(mws >> (16 * ct)) & 15u;
      __half2 m01 = lutm2[bits * 2], m23 = lutm2[bits * 2 + 1];
      fp16x2 p01 = __builtin_amdgcn_cvt_pkrtz(exp2f(s[ct][0]), exp2f(s[ct][1]));
      fp16x2 p23 = __builtin_amdgcn_cvt_pkrtz(exp2f(s[ct][2]), exp2f(s[ct][3]));
      f16x4 pc;
      ((__half2*)&pc)[0] = __hmul2(*(__half2*)&p01, m01);
      ((__half2*)&pc)[1] = __hmul2(*(__half2*)&p23, m23);
      pa[ct] = pc;
    }
  } else {
    const float tsc = exp2f(diff >= 143 ? c_pos : c_neg);
    const __half th = __float2half(tsc);
    const __half2 ts2{th, th};
#pragma unroll
    for (int ct = 0; ct < 4; ++ct) {
      unsigned bits = (unsigned)(mws >> (16 * ct)) & 15u;
      __half2 m01 = __hmul2(lutm2[bits * 2], ts2), m23 = __hmul2(lutm2[bits * 2 + 1], ts2);
      fp16x2 p01 = __builtin_amdgcn_cvt_pkrtz(exp2f(s[ct][0]), exp2f(s[ct][1]));
      fp16x2 p23 = __builtin_amdgcn_cvt_pkrtz(exp2f(s[ct][2]), exp2f(s[ct][3]));
      f16x4 pc;
      ((__half2*)&pc)[0] = __hmul2(*(__half2*)&p01, m01);
      ((__half2*)&pc)[1] = __hmul2(*(__half2*)&p23, m23);
      pa[ct] = pc;
    }
  }

  // PV depth-1 pipeline: prefetch next ct's V frags during current MFMAs
  __builtin_amdgcn_s_setprio(1);
#pragma unroll
  for (int dt = 0; dt < 4; ++dt)
    bvB[dt] = *(const f16x4*)(vbase + 1024 + dt * 128);
  osum = __builtin_amdgcn_mfma_f32_16x16x16f16(ones, pa[0], osum, 0, 0, 0);
#pragma unroll
  for (int dt = 0; dt < 4; ++dt)
    o[dt] = __builtin_amdgcn_mfma_f32_16x16x16f16(bvA[dt], pa[0], o[dt], 0, 0, 0);

#pragma unroll
  for (int dt = 0; dt < 4; ++dt)
    bvA[dt] = *(const f16x4*)(vbase + 2048 + dt * 128);
  osum = __builtin_amdgcn_mfma_f32_16x16x16f16(ones, pa[1], osum, 0, 0, 0);
#pragma unroll
  for (int dt = 0; dt < 4; ++dt)
    o[dt] = __builtin_amdgcn_mfma_f32_16x16x16f16(bvB[dt], pa[1], o[dt], 0, 0, 0);

#pragma unroll
  for (int dt = 0; dt < 4; ++dt)
    bvB[dt] = *(const f16x4*)(vbase + 3072 + dt * 128);
  osum = __builtin_amdgcn_mfma_f32_16x16x16f16(ones, pa[2], osum, 0, 0, 0);
#pragma unroll
  for (int dt = 0; dt < 4; ++dt)
    o[dt] = __builtin_amdgcn_mfma_f32_16x16x16f16(bvA[dt], pa[2], o[dt], 0, 0, 0);

  osum = __builtin_amdgcn_mfma_f32_16x16x16f16(ones, pa[3], osum, 0, 0, 0);
#pragma unroll
  for (int dt = 0; dt < 4; ++dt)
    o[dt] = __builtin_amdgcn_mfma_f32_16x16x16f16(bvB[dt], pa[3], o[dt], 0, 0, 0);
  __builtin_amdgcn_s_setprio(0);
}

__global__ __launch_bounds__(256, 4) void attn(
    const __half* __restrict__ Qh, const __half* __restrict__ Kh,
    const __half* __restrict__ Vt, const unsigned long long* __restrict__ mb64,
    const float* __restrict__ tab, __half* __restrict__ AO) {
  const int id = blockIdx.x;
  const int ii = id >> 3;
  const int bh = (id & 7) * 4 + (ii >> 5);  // XCD-pinning swizzle (bijective)
  const int q0 = (ii & 31) * 64;
  const int b = bh >> 4, h = bh & 15;
  const int t = threadIdx.x, lane = t & 63, w = t >> 6;  // w 0..3
  const int lg = lane >> 4, lr = lane & 15;

  __shared__ __align__(16) __half sK[2][64 * 64];
  __shared__ __align__(16) __half sV[2][64 * 64];
  __shared__ float sbias[260];  // bias(rel) for rel in [-128,128]; const outside
  __shared__ __align__(8) __half lutm[16][4];

  for (int i = t; i < 257; i += 256) sbias[i] = tab[h * 4095 + 1919 + i];
  if (t < 64) {
    int e = t >> 2, j = t & 3;
    lutm[e][j] = ((e >> j) & 1) ? __half(1.0f) : __half(0.0f);
  }

  const size_t bh2048 = (size_t)bh * 2048;
  const int qrow = q0 + w * 16 + lr;  // this lane's q-row
  const __half* qp = Qh + (bh2048 + qrow) * 64 + lg * 8;
  f16x8 aq0 = *(const f16x8*)qp;
  f16x8 aq1 = *(const f16x8*)(qp + 32);

  const __half* Kb = Kh + bh2048 * 64;
  const __half* Vb = Vt + bh2048 * 64;  // [256 kseg][64 d][8] per bh
  const unsigned long long* mrow = mb64 + ((size_t)(b * 2048 + qrow)) * 32;

  f32x4 o[4] = {};
  f32x4 osum = {};  // softmax denominators via ones-MFMA
  const f16x4 ones = {(_Float16)1.f, (_Float16)1.f, (_Float16)1.f, (_Float16)1.f};
  const __half2* lutm2 = (const __half2*)&lutm[0][0];

  unsigned long long mw0 = mrow[0], mw1 = mrow[1];

  stage_kv(Kb, Vb, 0, sK[0], sV[0], t);
  __syncthreads();  // tile 0 staged + sbias/lut ready
  const float c_neg = sbias[0], c_pos = sbias[256];
  const int dbase = -q0 - w * 16;

  for (int k0 = 0; k0 < L_; k0 += 128) {
    // body A: stage tile k0+64 -> buf1; compute tile k0 from buf0
    stage_kv(Kb, Vb, k0 + 64, sK[1], sV[1], t);
    unsigned long long mwa = mrow[(k0 >> 6) + 2];  // may read 8B past row: benign (ws)
    attn_tile(sK[0], sV[0], mw0, k0 + dbase, aq0, aq1, sbias, lutm2,
              c_neg, c_pos, lg, lr, o, osum, ones);
    __syncthreads();

    // body B: stage tile k0+128 -> buf0; compute tile k0+64 from buf1
    if (k0 + 128 < L_) stage_kv(Kb, Vb, k0 + 128, sK[0], sV[0], t);
    unsigned long long mwb = mrow[(k0 >> 6) + 3];
    attn_tile(sK[1], sV[1], mw1, k0 + 64 + dbase, aq0, aq1, sbias, lutm2,
              c_neg, c_pos, lg, lr, o, osum, ones);
    __syncthreads();

    mw0 = mwa;
    mw1 = mwb;
  }
  // epilogue: O[d=dt*16+4lg+r][q=lr]; osum[any reg] = denominator for q=lr
  const float rl = 1.0f / osum[0];
  const size_t qbase = ((size_t)(b * L_ + q0 + w * 16 + lr)) * D_ + h * 64;
#pragma unroll
  for (int dt = 0; dt < 4; ++dt) {
    f16x4 ov;
#pragma unroll
    for (int r = 0; r < 4; ++r) ov[r] = (_Float16)(o[dt][r] * rl);
    *(f16x4*)(AO + qbase + dt * 16 + 4 * lg) = ov;
  }
}

// ---------------- launch ----------------
extern "C" void kernel_launch(void* const* d_in, const int* in_sizes, int n_in,
                              void* d_out, int out_size, void* d_ws, size_t ws_size,
                              hipStream_t stream) {
  const float* x = (const float*)d_in[0];
  const int* mask = (const int*)d_in[1];
  const float* Wq_w = (const float*)d_in[2];
  const float* Wq_b = (const float*)d_in[3];
  const float* Wk_w = (const float*)d_in[4];
  const float* Wk_b = (const float*)d_in[5];
  const float* Wv_w = (const float*)d_in[6];
  const float* Wv_b = (const float*)d_in[7];
  const float* Wo_w = (const float*)d_in[8];
  const float* Wo_b = (const float*)d_in[9];
  const float* rel_emb = (const float*)d_in[10];
  float* out = (float*)d_out;

  char* ws = (char*)d_ws;
  const size_t MB = 1024 * 1024;
  __half* xh = (__half*)(ws);              // 8 MiB, reused as AO
  __half* wqh = (__half*)(ws + 8 * MB);
  __half* wkh = (__half*)(ws + 10 * MB);
  __half* wvh = (__half*)(ws + 12 * MB);
  __half* woh = (__half*)(ws + 14 * MB);
  __half* Qh = (__half*)(ws + 16 * MB);    // [32][2048][64]
  __half* Kh = (__half*)(ws + 24 * MB);
  __half* Vt = (__half*)(ws + 32 * MB);    // [32][256][64][8]
  unsigned long long* mb64 = (unsigned long long*)(ws + 40 * MB);  // 1 MiB
  float* tab = (float*)(ws + 48 * MB);     // 256 KiB
  __half* AO = xh;

  prep<<<4352, 256, 0, stream>>>(x, Wq_w, Wk_w, Wv_w, Wo_w, mask, rel_emb,
                                 xh, wqh, wkh, wvh, woh, mb64, tab);
  gemm_qkv<<<768, 256, 0, stream>>>(xh, wqh, wkh, wvh, Wq_b, Wk_b, Wv_b, Qh, Kh, Vt);
  attn<<<1024, 256, 0, stream>>>(Qh, Kh, Vt, mb64, tab, AO);
  gemm_out<<<1024, 256, 0, stream>>>(AO, woh, Wo_b, out);
}

// Round 18
// 162.739 us; speedup vs baseline: 1.0103x; 1.0103x over previous
//
#include <hip/hip_runtime.h>
#include <hip/hip_fp16.h>

#define B_ 2
#define L_ 2048
#define D_ 1024
#define H_ 16

typedef __attribute__((ext_vector_type(8))) _Float16 f16x8;
typedef __attribute__((ext_vector_type(4))) _Float16 f16x4;
typedef __attribute__((ext_vector_type(2))) __fp16 fp16x2;
typedef __attribute__((ext_vector_type(4))) float f32x4;

#define LOG2E 1.44269504088896f

__device__ __forceinline__ void gload_lds16(const void* g, void* l) {
  __builtin_amdgcn_global_load_lds(
      (const __attribute__((address_space(1))) unsigned int*)g,
      (__attribute__((address_space(3))) unsigned int*)l, 16, 0, 0);
}

// ---------------- merged prep (grid-stride, 4352 blocks) ----------------
__global__ __launch_bounds__(256) void prep(
    const float* __restrict__ x, const float* __restrict__ Wq,
    const float* __restrict__ Wk, const float* __restrict__ Wv,
    const float* __restrict__ Wo, const int* __restrict__ m,
    const float* __restrict__ rel_emb,
    __half* __restrict__ xh, __half* __restrict__ wqh, __half* __restrict__ wkh,
    __half* __restrict__ wvh, __half* __restrict__ woh,
    unsigned long long* __restrict__ bits, float* __restrict__ tab) {
  const int bid = blockIdx.x;
  if (bid < 2048) {
#pragma unroll
    for (int kk = 0; kk < 4; ++kk) {
      int i = bid * 1024 + kk * 256 + threadIdx.x;  // 2M float4 groups
      const float* src;
      __half* dst;
      int j;
      if (i < 1048576) {
        src = x; dst = xh; j = i;
      } else {
        int k = i - 1048576;
        int wsel = k >> 18;
        j = k & 262143;
        src = wsel == 0 ? Wq : (wsel == 1 ? Wk : (wsel == 2 ? Wv : Wo));
        dst = wsel == 0 ? wqh : (wsel == 1 ? wkh : (wsel == 2 ? wvh : woh));
      }
      float4 v = ((const float4*)src)[j];
      __half2* o = (__half2*)(dst + (size_t)j * 4);
      o[0] = __floats2half2_rn(v.x, v.y);
      o[1] = __floats2half2_rn(v.z, v.w);
    }
  } else if (bid < 4096) {
    int gw = (bid - 2048) * 4 + (threadIdx.x >> 6);  // wave id [0,8192)
    int lane = threadIdx.x & 63;
#pragma unroll
    for (int j = 0; j < 16; ++j) {
      int wword = gw * 16 + j;  // 131072 words total
      int v = m[(size_t)wword * 64 + lane];
      unsigned long long bal = __ballot(v != 0);
      if (lane == 0) bits[wword] = bal;
    }
  } else {
    int i = (bid - 4096) * 256 + threadIdx.x;
    if (i >= H_ * 4095) return;
    int h = i / 4095, idx = i - h * 4095;
    int rel = idx - 2047;
    int n = rel < 0 ? -rel : rel;
    int bkt;
    if (n < 8) {
      bkt = n;
    } else {
      float t = logf((float)n / 8.0f) / 2.772588722239781f * 8.0f;
      int v = 8 + (int)t;
      bkt = v < 15 ? v : 15;
    }
    if (rel > 0) bkt += 16;
    tab[i] = rel_emb[bkt * H_ + h] * LOG2E;
  }
}

// ---------------- GEMM core 128x128 (m97-regime: grid-TLP hides drains) ----
template <bool CT>
__device__ __forceinline__ void gemm_tile(const __half* __restrict__ A,
                                          const __half* __restrict__ Bw,
                                          int m0, int n0,
                                          __half* sA, __half* sB,
                                          f32x4 (&acc)[4][4],
                                          int lane, int wm, int wn, int t) {
  for (int k0 = 0; k0 < 1024; k0 += 64) {
    __syncthreads();
#pragma unroll
    for (int it = 0; it < 4; ++it) {
      int c = t + it * 256;
      int row = c >> 3, seg = c & 7;
      gload_lds16(A + ((size_t)(m0 + row) << 10) + k0 + seg * 8, sA + c * 8);
      gload_lds16(Bw + ((size_t)(n0 + row) << 10) + k0 + seg * 8, sB + c * 8);
    }
    __syncthreads();
#pragma unroll
    for (int kk = 0; kk < 2; ++kk) {
      const int off = kk * 32 + (lane >> 4) * 8;
      const int rr = lane & 15;
      f16x8 af[4], bf[4];
#pragma unroll
      for (int i = 0; i < 4; ++i) af[i] = *(const f16x8*)&sA[(wm * 64 + i * 16 + rr) * 64 + off];
#pragma unroll
      for (int i = 0; i < 4; ++i) bf[i] = *(const f16x8*)&sB[(wn * 64 + i * 16 + rr) * 64 + off];
#pragma unroll
      for (int mi = 0; mi < 4; ++mi)
#pragma unroll
        for (int ni = 0; ni < 4; ++ni) {
          if (CT)
            acc[mi][ni] = __builtin_amdgcn_mfma_f32_16x16x32_f16(bf[ni], af[mi], acc[mi][ni], 0, 0, 0);
          else
            acc[mi][ni] = __builtin_amdgcn_mfma_f32_16x16x32_f16(af[mi], bf[ni], acc[mi][ni], 0, 0, 0);
        }
    }
  }
}

// fused QKV projection: grid 768 linear, XCD-chunked (4 m-panels per XCD)
// V output layout: Vt[bh][kseg=k/8][d][8 halves]
__global__ __launch_bounds__(256) void gemm_qkv(
    const __half* __restrict__ xh,
    const __half* __restrict__ Wq, const __half* __restrict__ Wk, const __half* __restrict__ Wv,
    const float* __restrict__ bq, const float* __restrict__ bk, const float* __restrict__ bvv,
    __half* __restrict__ Qh, __half* __restrict__ Kh, __half* __restrict__ Vt) {
  __shared__ __align__(16) __half sA[128 * 64];
  __shared__ __align__(16) __half sB[128 * 64];
  const int lin = blockIdx.x;
  const int xcd = lin & 7, idx = lin >> 3;        // 96 per XCD
  const int m0 = (xcd * 4 + (idx & 3)) * 128;     // 4 x-panels resident per XCD
  const int ng = (idx >> 2) * 128;                // weight panel shared by 4 consecutive blocks
  const int widx = ng >> 10;
  const int n0 = ng & 1023;
  const __half* Bw = widx == 0 ? Wq : (widx == 1 ? Wk : Wv);
  const float* bias = widx == 0 ? bq : (widx == 1 ? bk : bvv);
  const int t = threadIdx.x, lane = t & 63, w = t >> 6;
  const int wm = w >> 1, wn = w & 1;
  const int lg = lane >> 4, lr = lane & 15;
  f32x4 acc[4][4] = {};
  if (widx == 2) {
    gemm_tile<false>(xh, Bw, m0, n0, sA, sB, acc, lane, wm, wn, t);
    // V epilogue: Vt[bh][l>>3][dd][l&7 .. +3], one 8B store (l&7 in {0,4})
#pragma unroll
    for (int mi = 0; mi < 4; ++mi)
#pragma unroll
      for (int ni = 0; ni < 4; ++ni) {
        int m = m0 + wm * 64 + mi * 16 + lg * 4;
        int n = n0 + wn * 64 + ni * 16 + lr;
        float bvx = bias[n];
        int b = m >> 11, l = m & 2047, hh = n >> 6, dd = n & 63;
        f32x4 a = acc[mi][ni];
        size_t base = ((size_t)((b * 16 + hh) * 256 + (l >> 3))) * 512 + dd * 8 + (l & 7);
        f16x4 pv;
#pragma unroll
        for (int r = 0; r < 4; ++r) pv[r] = (_Float16)(a[r] + bvx);
        *(f16x4*)(Vt + base) = pv;
      }
  } else {
    gemm_tile<true>(xh, Bw, m0, n0, sA, sB, acc, lane, wm, wn, t);
    __half* dst = widx == 0 ? Qh : Kh;
    // fold 1/sqrt(dk) AND log2e into Q (softmax done in log2 domain)
    const float scf = widx == 0 ? 0.125f * LOG2E : 1.0f;
#pragma unroll
    for (int mi = 0; mi < 4; ++mi)
#pragma unroll
      for (int ni = 0; ni < 4; ++ni) {
        int m = m0 + wm * 64 + mi * 16 + lr;        // l index
        int n = n0 + wn * 64 + ni * 16 + 4 * lg;    // d index (4 consecutive)
        f32x4 bb = *(const f32x4*)&bias[n];
        int b = m >> 11, l = m & 2047, hh = n >> 6, dd = n & 63;
        f16x4 ov;
#pragma unroll
        for (int r = 0; r < 4; ++r) ov[r] = (_Float16)((acc[mi][ni][r] + bb[r]) * scf);
        *(f16x4*)(dst + (((size_t)(b * 16 + hh)) * 2048 + l) * 64 + dd) = ov;
      }
  }
}

// output projection: 64x64 tiles, grid 1024 = 4 blocks/CU (R12-exact: best total)
__global__ __launch_bounds__(256) void gemm_out(
    const __half* __restrict__ AO, const __half* __restrict__ Wo,
    const float* __restrict__ bo, float* __restrict__ out) {
  __shared__ __align__(16) __half sA[64 * 64];
  __shared__ __align__(16) __half sB[64 * 64];
  const int lin = blockIdx.x;
  const int xcd = lin & 7, idx = lin >> 3;       // 128 per XCD
  const int m0 = (xcd * 8 + (idx & 7)) * 64;     // 8 m-panels resident per XCD
  const int n0 = (idx >> 3) * 64;
  const int t = threadIdx.x, lane = t & 63, w = t >> 6;
  const int wm = w >> 1, wn = w & 1;             // 2x2 waves of 32x32
  const int lg = lane >> 4, lr = lane & 15;
  f32x4 acc[2][2] = {};
  for (int k0 = 0; k0 < 1024; k0 += 64) {
    __syncthreads();
#pragma unroll
    for (int it = 0; it < 2; ++it) {
      int c = t + it * 256;
      int row = c >> 3, seg = c & 7;
      gload_lds16(AO + ((size_t)(m0 + row) << 10) + k0 + seg * 8, sA + c * 8);
      gload_lds16(Wo + ((size_t)(n0 + row) << 10) + k0 + seg * 8, sB + c * 8);
    }
    __syncthreads();
#pragma unroll
    for (int kk = 0; kk < 2; ++kk) {
      const int off = kk * 32 + lg * 8;
      f16x8 af[2], bf[2];
#pragma unroll
      for (int i = 0; i < 2; ++i) af[i] = *(const f16x8*)&sA[(wm * 32 + i * 16 + lr) * 64 + off];
#pragma unroll
      for (int i = 0; i < 2; ++i) bf[i] = *(const f16x8*)&sB[(wn * 32 + i * 16 + lr) * 64 + off];
#pragma unroll
      for (int mi = 0; mi < 2; ++mi)
#pragma unroll
        for (int ni = 0; ni < 2; ++ni)
          acc[mi][ni] = __builtin_amdgcn_mfma_f32_16x16x32_f16(bf[ni], af[mi], acc[mi][ni], 0, 0, 0);
    }
  }
  // C^T epilogue: float4 stores
#pragma unroll
  for (int mi = 0; mi < 2; ++mi)
#pragma unroll
    for (int ni = 0; ni < 2; ++ni) {
      int mm = m0 + wm * 32 + mi * 16 + lr;
      int nn = n0 + wn * 32 + ni * 16 + 4 * lg;
      f32x4 bb = *(const f32x4*)&bo[nn];
      f32x4 vv;
#pragma unroll
      for (int r = 0; r < 4; ++r) vv[r] = acc[mi][ni][r] + bb[r];
      *(f32x4*)(out + (size_t)mm * 1024 + nn) = vv;
    }
}

// ---------------- flash attention (FROZEN R16: best measured 84.5us) ----------------
__device__ __forceinline__ void stage_kv(const __half* __restrict__ Kb,
                                         const __half* __restrict__ Vb, int kt,
                                         __half* kdst, __half* vdst, int t) {
#pragma unroll
  for (int it = 0; it < 2; ++it) {
    int c = t + it * 256;
    int row = c >> 3, seg = c & 7;
    int gs = (seg ^ row) & 7;
    gload_lds16(Kb + ((size_t)(kt + row) << 6) + gs * 8, kdst + c * 8);
    // V: slot (kq=c>>6, d=c&63) <- Vb[(kt/8 + kq)*512 + d*8], 16B coalesced
    gload_lds16(Vb + ((size_t)((kt >> 3) + (c >> 6)) << 9) + (c & 63) * 8, vdst + c * 8);
  }
}

__device__ __forceinline__ void attn_tile(
    const __half* kb, const __half* vb,
    unsigned long long mwv, int diff,
    f16x8 aq0, f16x8 aq1,
    const float* sbias, const __half2* lutm2,
    float c_neg, float c_pos, int lg, int lr,
    f32x4 (&o)[4], f32x4& osum, f16x4 ones) {
  // S^T = K Q^T (lane: q=lr, k=16ct+4lg+r); scale+log2e folded in Q
  __builtin_amdgcn_s_setprio(1);
  f32x4 s[4] = {};
#pragma unroll
  for (int ct = 0; ct < 4; ++ct) {
    int row = ct * 16 + lr;
    const __half* rb = &kb[row * 64];
    f16x8 kf0 = *(const f16x8*)(rb + ((8 * lg) ^ ((row & 7) << 3)));
    f16x8 kf1 = *(const f16x8*)(rb + ((32 + 8 * lg) ^ ((row & 7) << 3)));
    s[ct] = __builtin_amdgcn_mfma_f32_16x16x32_f16(kf0, aq0, s[ct], 0, 0, 0);
    s[ct] = __builtin_amdgcn_mfma_f32_16x16x32_f16(kf1, aq1, s[ct], 0, 0, 0);
  }
  __builtin_amdgcn_s_setprio(0);

  // V lane base: all 16 V reads = vbase + (ct*1024 + dt*128) halves (immediates)
  const __half* vbase = vb + ((lg >> 1) * 512 + lr * 8 + (lg & 1) * 4);

  // issue first V fragment group now: latency hides under softmax VALU
  f16x4 bvA[4], bvB[4];
#pragma unroll
  for (int dt = 0; dt < 4; ++dt)
    bvA[dt] = *(const f16x4*)(vbase + dt * 128);

  // bias: wave-uniform 3-way; const branches fold 2^c into the P scale
  float tsc = 1.0f;
  if (diff >= 143) {
    tsc = exp2f(c_pos);
  } else if (diff <= -191) {
    tsc = exp2f(c_neg);
  } else {
    const int ibase = diff + 4 * lg - lr + 128;
#pragma unroll
    for (int ct = 0; ct < 4; ++ct)
#pragma unroll
      for (int r = 0; r < 4; ++r) {
        int idx = ibase + 16 * ct + r;
        idx = idx < 0 ? 0 : (idx > 256 ? 256 : idx);
        s[ct][r] += sbias[idx];
      }
  }
  const __half th = __float2half(tsc);
  const __half2 ts2{th, th};

  // P = tsc * exp2(S) (no max shift; bounded), mask via f16 LUT multiply
  f16x4 pa[4];
#pragma unroll
  for (int ct = 0; ct < 4; ++ct) {
    unsigned bits = (unsigned)(mwv >> (16 * ct + 4 * lg)) & 15u;
    __half2 m01 = __hmul2(lutm2[bits * 2], ts2), m23 = __hmul2(lutm2[bits * 2 + 1], ts2);
    fp16x2 p01 = __builtin_amdgcn_cvt_pkrtz(exp2f(s[ct][0]), exp2f(s[ct][1]));
    fp16x2 p23 = __builtin_amdgcn_cvt_pkrtz(exp2f(s[ct][2]), exp2f(s[ct][3]));
    f16x4 pc;
    ((__half2*)&pc)[0] = __hmul2(*(__half2*)&p01, m01);
    ((__half2*)&pc)[1] = __hmul2(*(__half2*)&p23, m23);
    pa[ct] = pc;
  }

  // PV depth-1 pipeline: prefetch next ct's V frags during current MFMAs
  __builtin_amdgcn_s_setprio(1);
#pragma unroll
  for (int dt = 0; dt < 4; ++dt)
    bvB[dt] = *(const f16x4*)(vbase + 1024 + dt * 128);
  osum = __builtin_amdgcn_mfma_f32_16x16x16f16(ones, pa[0], osum, 0, 0, 0);
#pragma unroll
  for (int dt = 0; dt < 4; ++dt)
    o[dt] = __builtin_amdgcn_mfma_f32_16x16x16f16(bvA[dt], pa[0], o[dt], 0, 0, 0);

#pragma unroll
  for (int dt = 0; dt < 4; ++dt)
    bvA[dt] = *(const f16x4*)(vbase + 2048 + dt * 128);
  osum = __builtin_amdgcn_mfma_f32_16x16x16f16(ones, pa[1], osum, 0, 0, 0);
#pragma unroll
  for (int dt = 0; dt < 4; ++dt)
    o[dt] = __builtin_amdgcn_mfma_f32_16x16x16f16(bvB[dt], pa[1], o[dt], 0, 0, 0);

#pragma unroll
  for (int dt = 0; dt < 4; ++dt)
    bvB[dt] = *(const f16x4*)(vbase + 3072 + dt * 128);
  osum = __builtin_amdgcn_mfma_f32_16x16x16f16(ones, pa[2], osum, 0, 0, 0);
#pragma unroll
  for (int dt = 0; dt < 4; ++dt)
    o[dt] = __builtin_amdgcn_mfma_f32_16x16x16f16(bvA[dt], pa[2], o[dt], 0, 0, 0);

  osum = __builtin_amdgcn_mfma_f32_16x16x16f16(ones, pa[3], osum, 0, 0, 0);
#pragma unroll
  for (int dt = 0; dt < 4; ++dt)
    o[dt] = __builtin_amdgcn_mfma_f32_16x16x16f16(bvB[dt], pa[3], o[dt], 0, 0, 0);
  __builtin_amdgcn_s_setprio(0);
}

__global__ __launch_bounds__(256, 4) void attn(
    const __half* __restrict__ Qh, const __half* __restrict__ Kh,
    const __half* __restrict__ Vt, const unsigned long long* __restrict__ mb64,
    const float* __restrict__ tab, __half* __restrict__ AO) {
  const int id = blockIdx.x;
  const int ii = id >> 3;
  const int bh = (id & 7) * 4 + (ii >> 5);  // XCD-pinning swizzle (bijective)
  const int q0 = (ii & 31) * 64;
  const int b = bh >> 4, h = bh & 15;
  const int t = threadIdx.x, lane = t & 63, w = t >> 6;  // w 0..3
  const int lg = lane >> 4, lr = lane & 15;

  __shared__ __align__(16) __half sK[2][64 * 64];
  __shared__ __align__(16) __half sV[2][64 * 64];
  __shared__ float sbias[260];  // bias(rel) for rel in [-128,128]; const outside
  __shared__ __align__(8) __half lutm[16][4];

  for (int i = t; i < 257; i += 256) sbias[i] = tab[h * 4095 + 1919 + i];
  if (t < 64) {
    int e = t >> 2, j = t & 3;
    lutm[e][j] = ((e >> j) & 1) ? __half(1.0f) : __half(0.0f);
  }

  const size_t bh2048 = (size_t)bh * 2048;
  const int qrow = q0 + w * 16 + lr;  // this lane's q-row
  const __half* qp = Qh + (bh2048 + qrow) * 64 + lg * 8;
  f16x8 aq0 = *(const f16x8*)qp;
  f16x8 aq1 = *(const f16x8*)(qp + 32);

  const __half* Kb = Kh + bh2048 * 64;
  const __half* Vb = Vt + bh2048 * 64;  // [256 kseg][64 d][8] per bh
  const unsigned long long* mrow = mb64 + ((size_t)(b * 2048 + qrow)) * 32;

  f32x4 o[4] = {};
  f32x4 osum = {};  // softmax denominators via ones-MFMA
  const f16x4 ones = {(_Float16)1.f, (_Float16)1.f, (_Float16)1.f, (_Float16)1.f};
  const __half2* lutm2 = (const __half2*)&lutm[0][0];

  unsigned long long mw0 = mrow[0], mw1 = mrow[1];

  stage_kv(Kb, Vb, 0, sK[0], sV[0], t);
  __syncthreads();  // tile 0 staged + sbias/lut ready
  const float c_neg = sbias[0], c_pos = sbias[256];
  const int dbase = -q0 - w * 16;

  for (int k0 = 0; k0 < L_; k0 += 128) {
    // body A: stage tile k0+64 -> buf1; compute tile k0 from buf0
    stage_kv(Kb, Vb, k0 + 64, sK[1], sV[1], t);
    unsigned long long mwa = mrow[(k0 >> 6) + 2];  // may read 8B past row: benign (ws)
    attn_tile(sK[0], sV[0], mw0, k0 + dbase, aq0, aq1, sbias, lutm2,
              c_neg, c_pos, lg, lr, o, osum, ones);
    __syncthreads();

    // body B: stage tile k0+128 -> buf0; compute tile k0+64 from buf1
    if (k0 + 128 < L_) stage_kv(Kb, Vb, k0 + 128, sK[0], sV[0], t);
    unsigned long long mwb = mrow[(k0 >> 6) + 3];
    attn_tile(sK[1], sV[1], mw1, k0 + 64 + dbase, aq0, aq1, sbias, lutm2,
              c_neg, c_pos, lg, lr, o, osum, ones);
    __syncthreads();

    mw0 = mwa;
    mw1 = mwb;
  }
  // epilogue: O[d=dt*16+4lg+r][q=lr]; osum[any reg] = denominator for q=lr
  const float rl = 1.0f / osum[0];
  const size_t qbase = ((size_t)(b * L_ + q0 + w * 16 + lr)) * D_ + h * 64;
#pragma unroll
  for (int dt = 0; dt < 4; ++dt) {
    f16x4 ov;
#pragma unroll
    for (int r = 0; r < 4; ++r) ov[r] = (_Float16)(o[dt][r] * rl);
    *(f16x4*)(AO + qbase + dt * 16 + 4 * lg) = ov;
  }
}

// ---------------- launch ----------------
extern "C" void kernel_launch(void* const* d_in, const int* in_sizes, int n_in,
                              void* d_out, int out_size, void* d_ws, size_t ws_size,
                              hipStream_t stream) {
  const float* x = (const float*)d_in[0];
  const int* mask = (const int*)d_in[1];
  const float* Wq_w = (const float*)d_in[2];
  const float* Wq_b = (const float*)d_in[3];
  const float* Wk_w = (const float*)d_in[4];
  const float* Wk_b = (const float*)d_in[5];
  const float* Wv_w = (const float*)d_in[6];
  const float* Wv_b = (const float*)d_in[7];
  const float* Wo_w = (const float*)d_in[8];
  const float* Wo_b = (const float*)d_in[9];
  const float* rel_emb = (const float*)d_in[10];
  float* out = (float*)d_out;

  char* ws = (char*)d_ws;
  const size_t MB = 1024 * 1024;
  __half* xh = (__half*)(ws);              // 8 MiB, reused as AO
  __half* wqh = (__half*)(ws + 8 * MB);
  __half* wkh = (__half*)(ws + 10 * MB);
  __half* wvh = (__half*)(ws + 12 * MB);
  __half* woh = (__half*)(ws + 14 * MB);
  __half* Qh = (__half*)(ws + 16 * MB);    // [32][2048][64]
  __half* Kh = (__half*)(ws + 24 * MB);
  __half* Vt = (__half*)(ws + 32 * MB);    // [32][256][64][8]
  unsigned long long* mb64 = (unsigned long long*)(ws + 40 * MB);  // 1 MiB
  float* tab = (float*)(ws + 48 * MB);     // 256 KiB
  __half* AO = xh;

  prep<<<4352, 256, 0, stream>>>(x, Wq_w, Wk_w, Wv_w, Wo_w, mask, rel_emb,
                                 xh, wqh, wkh, wvh, woh, mb64, tab);
  gemm_qkv<<<768, 256, 0, stream>>>(xh, wqh, wkh, wvh, Wq_b, Wk_b, Wv_b, Qh, Kh, Vt);
  attn<<<1024, 256, 0, stream>>>(Qh, Kh, Vt, mb64, tab, AO);
  gemm_out<<<1024, 256, 0, stream>>>(AO, woh, Wo_b, out);
}